// Round 3
// baseline (457.046 us; speedup 1.0000x reference)
//
#include <hip/hip_runtime.h>
#include <stdint.h>

// Stage1Assigner (RPN matcher + subsample + top-k per GT) for MI355X.
// B=8 images, A=200000 anchors, G=64 GTs, K=4, thresholds 0.3/0.7, 128 max pos.
//
// PRNG: JAX threefry, jax_threefry_partitionable=True:
//   keys[b] = threefry2x32((0,42),(0,b));  bits[a] = y0^y1 of threefry2x32(key_b,(0,a))
// Selection of 128 positives = 128 lexicographically smallest (bits>>9, a).
//
// R10 vs R9 (counter-driven): R9 total 322us but hot dispatch only 203us ->
// ~119us in SIX tail dispatches (launch latency on a dependency chain +
// redundant work: k_collect re-read the 16KB hist and redid bin-select in all
// 784 blocks; k_count redid the Tstar binary search in all 784 blocks). R10
// fuses the ENTIRE tail into ONE kernel k_tail, grid (B)=8 blocks x 1024
// threads; all per-image state (top4, hist, fine, cnt, npos, fcnt, binsel)
// lives in LDS (~37KB). Phases are verbatim copies of the R9 kernels,
// sequenced by __syncthreads() (orders global+shared within the block; the
// only cross-thread global handoff is posA atomicOr -> post-barrier reads).
// 7 dispatches -> 2. Hot kernel untouched except removing the now-dead
// global zero-init (cnt/npos/fcnt are LDS now).
//
// Hot-kernel structure (one 512-thread block per (slice,b), 8 waves, wave w
// handles gt-groups {2w, 2w+1} so its >=0.7 mask stays within one 32-gt half):
//   pass 1: per-gt per-lane MAX of approx q = inter*rcp(uni) (1 v_max; no div,
//           no branch). Screen threshold = 4th-largest of the 64 lane maxima
//           (merge network over (max,0,0,0) quads) which is <= the true 4th
//           largest approx value -> conservative; equal ~91% of the time.
//           t~ = bits(min(Q4lb - 16ulp, 0.7f - 8ulp)) - 8ulp  (safe: rcp err
//           <= ~2.5 ulp << 16-ulp slack; 8-ulp product margin covers binade
//           edges; denormal flush -> never-skip).
//   pass 2: conservative screen inter >= t~ * uni; survivors only: exact f32
//           div, exact >=0.7 bit, ballot-guarded u64 top-4 insert.
// All EXACT comparisons identical to R5/R7/R9 -> bit-identical output.
// Value-0 fake entries (masked lanes insert vb=0 early) are displaced whenever
// a gt has >=4 anchors with iou>0 globally (guaranteed for uniform boxes).
//
// IoU is fp-contract(off) IEEE per-op: identical bits across all passes and
// matches XLA per-HLO rounding.

#pragma clang fp contract(off)

#define B_IMG 8
#define A_N 200000
#define G_N 64
#define K_TOP 4
#define MAX_POS 128
#define FINE_CAP 4096
#define AS 2048
#define NS 98            // ceil(200000/2048)
#define WPS 32           // u64 ballot words per slice
#define NWORD 3136       // NS*WPS words of pos bits per image

typedef unsigned long long u64;
typedef unsigned int u32;

__device__ __forceinline__ u32 rotl32(u32 v, int n) { return (v << n) | (v >> (32 - n)); }

__device__ __forceinline__ void tf_round(u32& x0, u32& x1, int r) {
  x0 += x1; x1 = rotl32(x1, r); x1 ^= x0;
}

__device__ __forceinline__ void threefry2x32(u32 k0, u32 k1, u32& x0, u32& x1) {
  u32 ks2 = 0x1BD11BDAu ^ k0 ^ k1;
  x0 += k0; x1 += k1;
  tf_round(x0,x1,13); tf_round(x0,x1,15); tf_round(x0,x1,26); tf_round(x0,x1,6);
  x0 += k1; x1 += ks2 + 1u;
  tf_round(x0,x1,17); tf_round(x0,x1,29); tf_round(x0,x1,16); tf_round(x0,x1,24);
  x0 += ks2; x1 += k0 + 2u;
  tf_round(x0,x1,13); tf_round(x0,x1,15); tf_round(x0,x1,26); tf_round(x0,x1,6);
  x0 += k0; x1 += k1 + 3u;
  tf_round(x0,x1,17); tf_round(x0,x1,29); tf_round(x0,x1,16); tf_round(x0,x1,24);
  x0 += k1; x1 += ks2 + 4u;
  tf_round(x0,x1,13); tf_round(x0,x1,15); tf_round(x0,x1,26); tf_round(x0,x1,6);
  x0 += ks2; x1 += k0 + 5u;
}

__device__ __forceinline__ void image_key(int b, u32& kb0, u32& kb1) {
  u32 x0 = 0u, x1 = (u32)b;
  threefry2x32(0u, 42u, x0, x1);
  kb0 = x0; kb1 = x1;
}

__device__ __forceinline__ u32 rbits_for(u32 k0, u32 k1, u32 a) {
  u32 x0 = 0u, x1 = a;
  threefry2x32(k0, k1, x0, x1);
  return x0 ^ x1;
}

__device__ __forceinline__ void conv_box(float4 bx, float& x0, float& y0,
                                         float& x1, float& y1, float& area) {
  #pragma clang fp contract(off)
  x0 = bx.x - 0.5f * bx.z;
  y0 = bx.y - 0.5f * bx.w;
  x1 = bx.x + 0.5f * bx.z;
  y1 = bx.y + 0.5f * bx.w;
  area = (x1 - x0) * (y1 - y0);
}

__device__ __forceinline__ float iou_pair(float ax0, float ay0, float ax1, float ay1, float aarea,
                                          float gx0, float gy0, float gx1, float gy1, float garea) {
  #pragma clang fp contract(off)
  float ltx = fmaxf(gx0, ax0), lty = fmaxf(gy0, ay0);
  float rbx = fminf(gx1, ax1), rby = fminf(gy1, ay1);
  float w = fmaxf(rbx - ltx, 0.0f), h = fmaxf(rby - lty, 0.0f);
  float inter = w * h;
  float uni = (garea + aarea) - inter;
  return inter / uni;
}

// inter/uni only (no division) — same rounding sequence as iou_pair's prefix.
__device__ __forceinline__ void iou_parts(float ax0, float ay0, float ax1, float ay1, float aarea,
                                          float gx0, float gy0, float gx1, float gy1, float garea,
                                          float& inter, float& uni) {
  #pragma clang fp contract(off)
  float ltx = fmaxf(gx0, ax0), lty = fmaxf(gy0, ay0);
  float rbx = fminf(gx1, ax1), rby = fminf(gy1, ay1);
  float w = fmaxf(rbx - ltx, 0.0f), h = fmaxf(rby - lty, 0.0f);
  inter = w * h;
  uni = (garea + aarea) - inter;
}

__device__ __forceinline__ void top4_insert(u64 (&top)[4], u64 key) {
  if (key > top[3]) {
    if (key > top[0])      { top[3]=top[2]; top[2]=top[1]; top[1]=top[0]; top[0]=key; }
    else if (key > top[1]) { top[3]=top[2]; top[2]=top[1]; top[1]=key; }
    else if (key > top[2]) { top[3]=top[2]; top[2]=key; }
    else                   { top[3]=key; }
  }
}

__device__ __forceinline__ void wave_merge_top4(u64 (&top)[4]) {
  for (int off = 32; off >= 1; off >>= 1) {
    u64 o[4];
    #pragma unroll
    for (int k = 0; k < 4; k++) o[k] = __shfl_down(top[k], (unsigned)off);
    u64 m[4]; int i = 0, j = 0;
    #pragma unroll
    for (int k = 0; k < 4; k++) m[k] = (top[i] >= o[j]) ? top[i++] : o[j++];
    #pragma unroll
    for (int k = 0; k < 4; k++) top[k] = m[k];
  }
}

__device__ __forceinline__ void wave_merge_top4_u32(u32 (&top)[4]) {
  for (int off = 32; off >= 1; off >>= 1) {
    u32 o[4];
    #pragma unroll
    for (int k = 0; k < 4; k++) o[k] = __shfl_down(top[k], (unsigned)off);
    u32 m[4]; int i = 0, j = 0;
    #pragma unroll
    for (int k = 0; k < 4; k++) m[k] = (top[i] >= o[j]) ? top[i++] : o[j++];
    #pragma unroll
    for (int k = 0; k < 4; k++) top[k] = m[k];
  }
}

// conservative screen threshold: t~ = bitcast(max(tau,8)-8)  (tau = f32 bits)
__device__ __forceinline__ float screen_thresh(u32 tau) {
  u32 tb = (tau > 8u) ? (tau - 8u) : 0u;
  return __uint_as_float(tb);
}

// ---------------- Kernel 1: per-(slice, b) top-4 + pos-bit ballot ----------------
// grid (NS, B); block 512 = 8 waves; wave w handles gt-groups {2w, 2w+1}
// (so each wave's >=0.7 mask stays within one 32-gt half).
// launch_bounds (512,4): VGPR cap 128 — allocator lands at 56, no spill
// (R8's (512,8) capped at 64 and spilled: VGPR 32, WRITE_SIZE 502MB).
__launch_bounds__(512, 4)
__global__ void k_top4_part(const float4* __restrict__ anchors, const float4* __restrict__ gt,
                            u64* __restrict__ partial,
                            u64* __restrict__ posA, u64* __restrict__ posB) {
  const int s = blockIdx.x;
  const int b = blockIdx.y;
  const int t = threadIdx.x;
  const int wave = t >> 6, lane = t & 63;

  __shared__ float4 sxy[AS];        // converted xyxy; reused as wm after gp loop
  __shared__ float  sg[5][64];
  u32* wm = (u32*)sxy;

  const int base = s * AS;
  const int acnt = min(AS, A_N - base);
  const float4* ab = anchors + (size_t)b * A_N + base;

  for (int j = t; j < acnt; j += 512) {
    float x0, y0, x1, y1, ar;
    conv_box(ab[j], x0, y0, x1, y1, ar);
    sxy[j] = make_float4(x0, y0, x1, y1);
  }
  if (t < 64) {
    float x0, y0, x1, y1, ar;
    conv_box(gt[(size_t)b * G_N + t], x0, y0, x1, y1, ar);
    sg[0][t] = x0; sg[1][t] = y0; sg[2][t] = x1; sg[3][t] = y1; sg[4][t] = ar;
  }
  __syncthreads();

  u32 m = 0;   // bit k: anchor base+64k+lane has iou>=0.7 vs any of this wave's gts
  for (int gg = 0; gg < 2; gg++) {
    const int gp = wave * 2 + gg;      // 0..15
    const int gi = gp * 4;             // global gt index of group start
    const float g0x0 = sg[0][gi],   g0y0 = sg[1][gi],   g0x1 = sg[2][gi],   g0y1 = sg[3][gi],   g0a = sg[4][gi];
    const float g1x0 = sg[0][gi+1], g1y0 = sg[1][gi+1], g1x1 = sg[2][gi+1], g1y1 = sg[3][gi+1], g1a = sg[4][gi+1];
    const float g2x0 = sg[0][gi+2], g2y0 = sg[1][gi+2], g2x1 = sg[2][gi+2], g2y1 = sg[3][gi+2], g2a = sg[4][gi+2];
    const float g3x0 = sg[0][gi+3], g3y0 = sg[1][gi+3], g3x1 = sg[2][gi+3], g3y1 = sg[3][gi+3], g3a = sg[4][gi+3];

    // ---- pass 1: per-gt per-lane MAX of approx q (no div, no index, no branch) ----
    u32 q0 = 0, q1 = 0, q2 = 0, q3 = 0;
    for (int j = lane; j < acnt; j += 64) {
      float4 x = sxy[j];
      float aarea = (x.z - x.x) * (x.w - x.y);
      float i0, u0, i1, u1, i2, u2, i3, u3;
      iou_parts(x.x, x.y, x.z, x.w, aarea, g0x0, g0y0, g0x1, g0y1, g0a, i0, u0);
      iou_parts(x.x, x.y, x.z, x.w, aarea, g1x0, g1y0, g1x1, g1y1, g1a, i1, u1);
      iou_parts(x.x, x.y, x.z, x.w, aarea, g2x0, g2y0, g2x1, g2y1, g2a, i2, u2);
      iou_parts(x.x, x.y, x.z, x.w, aarea, g3x0, g3y0, g3x1, g3y1, g3a, i3, u3);
      q0 = max(q0, __float_as_uint(i0 * __builtin_amdgcn_rcpf(u0)));
      q1 = max(q1, __float_as_uint(i1 * __builtin_amdgcn_rcpf(u1)));
      q2 = max(q2, __float_as_uint(i2 * __builtin_amdgcn_rcpf(u2)));
      q3 = max(q3, __float_as_uint(i3 * __builtin_amdgcn_rcpf(u3)));
    }
    // 4th-largest of the 64 lane maxima: a LOWER bound on the true 4th-largest
    // approx value (the top-4 lane maxima are 4 distinct data values) -> the
    // screen below stays conservative; almost always equal to the true 4th.
    u32 Q0[4] = {q0,0,0,0}, Q1[4] = {q1,0,0,0}, Q2[4] = {q2,0,0,0}, Q3[4] = {q3,0,0,0};
    wave_merge_top4_u32(Q0);
    wave_merge_top4_u32(Q1);
    wave_merge_top4_u32(Q2);
    wave_merge_top4_u32(Q3);
    // wave-uniform Q4 with 16-ulp rcp slack, capped by (0.7f - 8ulp)
    u32 Q40 = __shfl(Q0[3], 0), Q41 = __shfl(Q1[3], 0);
    u32 Q42 = __shfl(Q2[3], 0), Q43 = __shfl(Q3[3], 0);
    const u32 L7 = 0x3F333333u - 8u;   // 0.7f bits - 8 ulp
    float t0 = screen_thresh(min(Q40 > 16u ? Q40 - 16u : 0u, L7));
    float t1 = screen_thresh(min(Q41 > 16u ? Q41 - 16u : 0u, L7));
    float t2 = screen_thresh(min(Q42 > 16u ? Q42 - 16u : 0u, L7));
    float t3 = screen_thresh(min(Q43 > 16u ? Q43 - 16u : 0u, L7));

    // ---- pass 2: screened exact top-4 + >=0.7 bits ----
    u64 T0[4] = {0,0,0,0}, T1[4] = {0,0,0,0}, T2[4] = {0,0,0,0}, T3[4] = {0,0,0,0};
    u32 h0 = 0, h1 = 0, h2 = 0, h3 = 0;
    u32 bit = 1u;
    for (int j = lane; j < acnt; j += 64, bit <<= 1) {
      float4 x = sxy[j];
      float aarea = (x.z - x.x) * (x.w - x.y);
      float i0, u0, i1, u1, i2, u2, i3, u3;
      iou_parts(x.x, x.y, x.z, x.w, aarea, g0x0, g0y0, g0x1, g0y1, g0a, i0, u0);
      iou_parts(x.x, x.y, x.z, x.w, aarea, g1x0, g1y0, g1x1, g1y1, g1a, i1, u1);
      iou_parts(x.x, x.y, x.z, x.w, aarea, g2x0, g2y0, g2x1, g2y1, g2a, i2, u2);
      iou_parts(x.x, x.y, x.z, x.w, aarea, g3x0, g3y0, g3x1, g3y1, g3a, i3, u3);
      u32 ni = ~(u32)(base + j);
      bool s0 = (i0 >= t0 * u0), s1 = (i1 >= t1 * u1);
      bool s2 = (i2 >= t2 * u2), s3 = (i3 >= t3 * u3);
      if (__ballot(s0)) {
        float v = 0.0f;
        if (s0) { v = i0 / u0; if (v >= 0.7f) m |= bit; }
        u32 vb = __float_as_uint(v);
        bool ins = s0 && (vb >= h0);
        if (__ballot(ins)) {
          if (ins) top4_insert(T0, ((u64)vb << 32) | (u64)ni);
          h0 = (u32)(T0[3] >> 32);
        }
      }
      if (__ballot(s1)) {
        float v = 0.0f;
        if (s1) { v = i1 / u1; if (v >= 0.7f) m |= bit; }
        u32 vb = __float_as_uint(v);
        bool ins = s1 && (vb >= h1);
        if (__ballot(ins)) {
          if (ins) top4_insert(T1, ((u64)vb << 32) | (u64)ni);
          h1 = (u32)(T1[3] >> 32);
        }
      }
      if (__ballot(s2)) {
        float v = 0.0f;
        if (s2) { v = i2 / u2; if (v >= 0.7f) m |= bit; }
        u32 vb = __float_as_uint(v);
        bool ins = s2 && (vb >= h2);
        if (__ballot(ins)) {
          if (ins) top4_insert(T2, ((u64)vb << 32) | (u64)ni);
          h2 = (u32)(T2[3] >> 32);
        }
      }
      if (__ballot(s3)) {
        float v = 0.0f;
        if (s3) { v = i3 / u3; if (v >= 0.7f) m |= bit; }
        u32 vb = __float_as_uint(v);
        bool ins = s3 && (vb >= h3);
        if (__ballot(ins)) {
          if (ins) top4_insert(T3, ((u64)vb << 32) | (u64)ni);
          h3 = (u32)(T3[3] >> 32);
        }
      }
    }
    wave_merge_top4(T0);
    wave_merge_top4(T1);
    wave_merge_top4(T2);
    wave_merge_top4(T3);
    if (lane == 0) {
      u64* dst = partial + (((size_t)b * NS + s) * G_N + gi) * 4;
      #pragma unroll
      for (int k = 0; k < 4; k++) {
        dst[k] = T0[k]; dst[4 + k] = T1[k]; dst[8 + k] = T2[k]; dst[12 + k] = T3[k];
      }
    }
  }

  __syncthreads();      // all waves done reading sxy (wm aliases it)
  wm[t] = m;
  __syncthreads();
  // waves 0-3 (threads 0..255) handled gts 0..31 -> posA; waves 4-7 -> posB.
  if (wave == 0 || wave == 4) {
    const u32* wmh = wm + (wave & 4) * 64;
    u32 mc = wmh[lane] | wmh[64 + lane] | wmh[128 + lane] | wmh[192 + lane];
    u64* posH = (wave ? posB : posA) + (size_t)b * NWORD + s * WPS;
    for (int k = 0; k < WPS; k++) {
      u64 bal = __ballot((mc >> k) & 1u);
      if (lane == 0) posH[k] = bal;    // plain store — every word covered exactly once
    }
  }
}

// ---------------- Kernel 2: fused tail — one block per image ----------------
// Phases (verbatim ports of the R9 kernels, sequenced by __syncthreads):
//   1. merge partials -> per-gt top4 (LDS); lq anchors -> posA (atomicOr)
//   2. pos-word scan: npos + threefry hist (LDS atomics)
//   3. bin select (once per image, not once per 98 blocks)
//   4. collect fine candidates into LDS
//   5. Tstar binary search (wave 0, LDS fine list)
//   6. selected-anchor 64-gt argmax -> cnt (LDS)
//   7. write the 4 output streams
__launch_bounds__(1024, 1)
__global__ void k_tail(const float4* __restrict__ anchors, const float4* __restrict__ gt,
                       const u64* __restrict__ partial,
                       u64* __restrict__ posA, const u64* __restrict__ posB,
                       float* __restrict__ out, int sec) {
  const int b = blockIdx.x;
  const int t = threadIdx.x;
  const int wave = t >> 6, lane = t & 63;

  __shared__ u64  stop4[G_N][4];     // 2 KB  merged top-4 keys per gt
  __shared__ u32  shist[4096];       // 16 KB rand-bits histogram
  __shared__ u32  sfine[FINE_CAP];   // 16 KB fine candidates of selected bin
  __shared__ float sg[5][G_N];       // 1.25 KB gt boxes (xyxy + area)
  __shared__ u32  red[256];          // coarse hist sums
  __shared__ u32  scnt[G_N];         // selected count per gt
  __shared__ u32  snpos, sfcnt;
  __shared__ int  sbin, sbefore;
  __shared__ u64  sT;

  for (int i = t; i < 4096; i += 1024) shist[i] = 0;
  if (t < G_N) scnt[t] = 0;
  if (t == 0) { snpos = 0; sfcnt = 0; }
  if (t < G_N) {
    float x0, y0, x1, y1, ar;
    conv_box(gt[(size_t)b * G_N + t], x0, y0, x1, y1, ar);
    sg[0][t] = x0; sg[1][t] = y0; sg[2][t] = x1; sg[3][t] = y1; sg[4][t] = ar;
  }

  // ---- phase 1: merge partials (wave w -> gts 4w..4w+3); lq -> posA ----
  for (int gq = 0; gq < 4; gq++) {
    const int g = wave * 4 + gq;
    const u64* pb = partial + ((size_t)b * NS * G_N + g) * 4;
    u64 keys[7];                     // NS*4 = 392 -> <= 7 per lane
    int nk = 0;
    for (int i = lane; i < NS * 4; i += 64)
      keys[nk++] = pb[(size_t)(i >> 2) * (G_N * 4) + (i & 3)];
    u64 top[4] = {0ull, 0ull, 0ull, 0ull};
    for (int q = 0; q < nk; q++) top4_insert(top, keys[q]);
    wave_merge_top4(top);
    if (lane == 0) {
      #pragma unroll
      for (int k = 0; k < 4; k++) stop4[g][k] = top[k];
    }
    // low-quality matches: every partial entry whose value bits == hq bits.
    u32 hqb = (u32)(__shfl(top[0], 0) >> 32);
    for (int q = 0; q < nk; q++) {
      u64 key = keys[q];
      u32 aidx = ~(u32)key;
      if ((u32)(key >> 32) == hqb && aidx < A_N)
        atomicOr(&posA[(size_t)b * NWORD + (aidx >> 6)], 1ull << (aidx & 63));
    }
  }
  __syncthreads();   // orders posA atomics + stop4/shist/scnt init before use

  // ---- phase 2: npos + hist ----
  u32 k0, k1; image_key(b, k0, k1);
  const u64* pa = posA + (size_t)b * NWORD;
  const u64* pbw = posB + (size_t)b * NWORD;
  for (int i = t; i < NWORD; i += 1024) {
    u64 w = pa[i] | pbw[i];
    if (w) {
      atomicAdd(&snpos, (u32)__popcll(w));
      while (w) {
        int bit = __ffsll((long long)w) - 1; w &= w - 1;
        u32 a = (u32)(i * 64 + bit);
        atomicAdd(&shist[rbits_for(k0, k1, a) >> 20], 1u);
      }
    }
  }
  __syncthreads();

  // ---- phase 3: bin select (identical logic to R9 k_collect head) ----
  if (t < 256) {
    u32 local = 0;
    for (int j = 0; j < 16; j++) local += shist[t * 16 + j];
    red[t] = local;
  }
  __syncthreads();
  if (t == 0) {
    if (snpos <= MAX_POS) {
      sbin = -1; sbefore = 0;
    } else {
      u32 cum = 0; int chunk = 0;
      for (int i = 0; i < 256; i++) {
        if (cum + red[i] >= MAX_POS) { chunk = i; break; }
        cum += red[i];
      }
      int tb = chunk * 16; u32 before = cum;
      for (int j = 0; j < 16; j++) {
        u32 h = shist[chunk * 16 + j];
        if (before + h >= MAX_POS) { tb = chunk * 16 + j; break; }
        before += h;
      }
      sbin = tb; sbefore = (int)before;
    }
  }
  __syncthreads();

  // ---- phase 4: collect fine candidates of the selected bin ----
  if (sbin >= 0) {
    const int stb = sbin;
    for (int i = t; i < NWORD; i += 1024) {
      u64 w = pa[i] | pbw[i];
      while (w) {
        int bit = __ffsll((long long)w) - 1; w &= w - 1;
        u32 a = (u32)(i * 64 + bit);
        u32 rb = rbits_for(k0, k1, a);
        if ((int)(rb >> 20) != stb) continue;
        u32 idx = atomicAdd(&sfcnt, 1u);
        if (idx < FINE_CAP) sfine[idx] = (((rb >> 9) & 0x7FFu) << 18) | a;
      }
    }
  }
  __syncthreads();

  // ---- phase 5: Tstar binary search (wave 0; identical to R9 k_count head) ----
  if (wave == 0) {
    u64 T = ~0ull;
    if (sbin >= 0) {
      const int m = min((int)sfcnt, FINE_CAP);
      const u32 need = (u32)(MAX_POS - sbefore);   // >= 1
      u32 lo = 0, hi = (1u << 29) - 1;
      while (lo < hi) {
        u32 mid = lo + ((hi - lo) >> 1);
        u32 c = 0;
        for (int j = lane; j < m; j += 64) c += (sfine[j] <= mid) ? 1u : 0u;
        #pragma unroll
        for (int off = 32; off >= 1; off >>= 1) c += __shfl_xor(c, off);
        if (c >= need) hi = mid; else lo = mid + 1;   // uniform across wave
      }
      T = ((u64)(u32)sbin << 29) | (u64)lo;   // 41-bit threshold
    }
    if (lane == 0) sT = T;
  }
  __syncthreads();

  // ---- phase 6: selected-anchor argmax counts (identical predicate to R9) ----
  const u64 T = sT;
  const float4* ab = anchors + (size_t)b * A_N;
  for (int i = t; i < NWORD; i += 1024) {
    u64 w = pa[i] | pbw[i];
    while (w) {
      int bit = __ffsll((long long)w) - 1; w &= w - 1;
      u32 a = (u32)(i * 64 + bit);
      if (T != ~0ull) {
        u32 rb = rbits_for(k0, k1, a);
        if (((((u64)(rb >> 9)) << 18) | (u64)a) > T) continue;
      }
      float ax0, ay0, ax1, ay1, aar;
      conv_box(ab[a], ax0, ay0, ax1, ay1, aar);
      float bv = -1.0f; int g0 = 0;
      for (int g = 0; g < 64; g++) {
        float v = iou_pair(ax0, ay0, ax1, ay1, aar,
                           sg[0][g], sg[1][g], sg[2][g], sg[3][g], sg[4][g]);
        if (v > bv) { bv = v; g0 = g; }   // strict > = first max (jnp.argmax)
      }
      atomicAdd(&scnt[g0], 1u);
    }
  }
  __syncthreads();

  // ---- phase 7: output (identical to R9 k_out) ----
  if (t < G_N) {
    const int g = t;
    const u32 c = min(scnt[g], (u32)K_TOP);
    #pragma unroll
    for (int k = 0; k < 4; k++) {
      u64 key = stop4[g][k];
      u32 fb = (u32)(key >> 32);
      u32 aidx = ~(u32)key;
      bool valid = (u32)k < c;
      int o = b * (G_N * K_TOP) + g * K_TOP + k;
      out[0 * sec + o] = valid ? (float)aidx : -1.0f;          // pr_inds
      out[1 * sec + o] = valid ? (float)g : -1.0f;             // gt_inds
      out[2 * sec + o] = valid ? 1.0f : 0.0f;                  // valid mask
      out[3 * sec + o] = valid ? __uint_as_float(fb) : 0.0f;   // topk ious
    }
  }
}

extern "C" void kernel_launch(void* const* d_in, const int* in_sizes, int n_in,
                              void* d_out, int out_size, void* d_ws, size_t ws_size,
                              hipStream_t stream) {
  const float4* anchors = (const float4*)d_in[0];  // [B, A, 4] cxcywh
  const float4* gt      = (const float4*)d_in[1];  // [B, G, 4] cxcywh
  float* out = (float*)d_out;                      // 4 x [B, G*K] concatenated

  // Workspace layout (2,007,040 B <= R5/R7-proven 2,025,536 B extent):
  //   partial @ 0          (8*98*64*32 = 1,605,632)
  //   posA    @ 1,605,632  (200,704)  [fully ballot-stored — no init]
  //   posB    @ 1,806,336  (200,704)  [fully ballot-stored — no init]
  // All other per-image state (top4/hist/fine/binsel/npos/fcnt/cnt) lives in
  // k_tail's LDS.
  char* ws = (char*)d_ws;
  u64*  partial = (u64*)(ws);
  u64*  posA    = (u64*)(ws + 1605632);
  u64*  posB    = (u64*)(ws + 1806336);

  int sec = out_size / 4;  // 2048 = B*G*K

  k_top4_part<<<dim3(NS, B_IMG), 512, 0, stream>>>(anchors, gt, partial, posA, posB);
  k_tail     <<<dim3(B_IMG), 1024, 0, stream>>>(anchors, gt, partial, posA, posB, out, sec);
}

// Round 4
// 271.362 us; speedup vs baseline: 1.6843x; 1.6843x over previous
//
#include <hip/hip_runtime.h>
#include <stdint.h>

// Stage1Assigner (RPN matcher + subsample + top-k per GT) for MI355X.
// B=8 images, A=200000 anchors, G=64 GTs, K=4, thresholds 0.3/0.7, 128 max pos.
//
// PRNG: JAX threefry, jax_threefry_partitionable=True:
//   keys[b] = threefry2x32((0,42),(0,b));  bits[a] = y0^y1 of threefry2x32(key_b,(0,a))
// Selection of 128 positives = 128 lexicographically smallest (bits>>9, a).
//
// R11 vs R10 (counter-driven): R10's single-block-per-image fused tail ran at
// 1.3% occupancy (8 blocks / 256 CUs) and spilled -> 213us. REVERTED to the
// R9-proven 6-dispatch tail verbatim. The new win attacks the hot kernel
// instead: R9 ran TWO full passes over all 102M (anchor,gt) pairs (~30 VALU
// insts/pair). Pass 1 only produces a conservative LOWER bound on each gt's
// 4th-largest approx IoU -- a lower bound is also valid from a SAMPLE:
//   thrG[gt] = max over 8 sampled slices of (4th-of-lane-maxima of approx q)
//            <= sample-4th <= global-4th   (same slack chain as R8/R9).
// k_thresh computes thrG on slices 0..7 (16384 anchors, 8.2%); k_main is the
// R9 hot kernel with pass 1 DELETED, screening against the global per-gt
// threshold (tighter than R9's per-slice ones -> fewer survivors). All exact
// comparisons (screen form i >= t*u, exact f32 div, >=0.7 cap at L7,
// ballot-guarded u64 insert, hq-tie handling) identical -> bit-identical
// output: every global-top-4 anchor and every hq-tied anchor satisfies
// exact >= e4 >= thr + margins, so none can be screened out.
//   t~ = bits(min(thrG - 16ulp, 0.7f - 8ulp)) - 8ulp  (rcp err <= ~2.5 ulp
//   << 16-ulp slack; 8-ulp product margin covers binade edges; denormal
//   flush -> never-skip; thrG=0 -> screen passes everything -> safe).
// thr_part (8 imgs x 8 slices x 64 gts x u32 = 16384 B) aliases the top4
// region, which is written only later by k_top4_merge -> no workspace growth.
//
// Value-0 fake entries (masked lanes insert vb=0 early) are displaced whenever
// a gt has >=4 anchors with iou>0 globally (guaranteed for uniform boxes).
//
// IoU is fp-contract(off) IEEE per-op: identical bits across all passes and
// matches XLA per-HLO rounding.

#pragma clang fp contract(off)

#define B_IMG 8
#define A_N 200000
#define G_N 64
#define K_TOP 4
#define MAX_POS 128
#define FINE_CAP 4096
#define AS 2048
#define NS 98            // ceil(200000/2048)
#define SUB_NS 8         // sampled slices for the threshold pass
#define WPS 32           // u64 ballot words per slice
#define NWORD 3136       // NS*WPS words of pos bits per image

typedef unsigned long long u64;
typedef unsigned int u32;

__device__ __forceinline__ u32 rotl32(u32 v, int n) { return (v << n) | (v >> (32 - n)); }

__device__ __forceinline__ void tf_round(u32& x0, u32& x1, int r) {
  x0 += x1; x1 = rotl32(x1, r); x1 ^= x0;
}

__device__ __forceinline__ void threefry2x32(u32 k0, u32 k1, u32& x0, u32& x1) {
  u32 ks2 = 0x1BD11BDAu ^ k0 ^ k1;
  x0 += k0; x1 += k1;
  tf_round(x0,x1,13); tf_round(x0,x1,15); tf_round(x0,x1,26); tf_round(x0,x1,6);
  x0 += k1; x1 += ks2 + 1u;
  tf_round(x0,x1,17); tf_round(x0,x1,29); tf_round(x0,x1,16); tf_round(x0,x1,24);
  x0 += ks2; x1 += k0 + 2u;
  tf_round(x0,x1,13); tf_round(x0,x1,15); tf_round(x0,x1,26); tf_round(x0,x1,6);
  x0 += k0; x1 += k1 + 3u;
  tf_round(x0,x1,17); tf_round(x0,x1,29); tf_round(x0,x1,16); tf_round(x0,x1,24);
  x0 += k1; x1 += ks2 + 4u;
  tf_round(x0,x1,13); tf_round(x0,x1,15); tf_round(x0,x1,26); tf_round(x0,x1,6);
  x0 += ks2; x1 += k0 + 5u;
}

__device__ __forceinline__ void image_key(int b, u32& kb0, u32& kb1) {
  u32 x0 = 0u, x1 = (u32)b;
  threefry2x32(0u, 42u, x0, x1);
  kb0 = x0; kb1 = x1;
}

__device__ __forceinline__ u32 rbits_for(u32 k0, u32 k1, u32 a) {
  u32 x0 = 0u, x1 = a;
  threefry2x32(k0, k1, x0, x1);
  return x0 ^ x1;
}

__device__ __forceinline__ void conv_box(float4 bx, float& x0, float& y0,
                                         float& x1, float& y1, float& area) {
  #pragma clang fp contract(off)
  x0 = bx.x - 0.5f * bx.z;
  y0 = bx.y - 0.5f * bx.w;
  x1 = bx.x + 0.5f * bx.z;
  y1 = bx.y + 0.5f * bx.w;
  area = (x1 - x0) * (y1 - y0);
}

__device__ __forceinline__ float iou_pair(float ax0, float ay0, float ax1, float ay1, float aarea,
                                          float gx0, float gy0, float gx1, float gy1, float garea) {
  #pragma clang fp contract(off)
  float ltx = fmaxf(gx0, ax0), lty = fmaxf(gy0, ay0);
  float rbx = fminf(gx1, ax1), rby = fminf(gy1, ay1);
  float w = fmaxf(rbx - ltx, 0.0f), h = fmaxf(rby - lty, 0.0f);
  float inter = w * h;
  float uni = (garea + aarea) - inter;
  return inter / uni;
}

// inter/uni only (no division) — same rounding sequence as iou_pair's prefix.
__device__ __forceinline__ void iou_parts(float ax0, float ay0, float ax1, float ay1, float aarea,
                                          float gx0, float gy0, float gx1, float gy1, float garea,
                                          float& inter, float& uni) {
  #pragma clang fp contract(off)
  float ltx = fmaxf(gx0, ax0), lty = fmaxf(gy0, ay0);
  float rbx = fminf(gx1, ax1), rby = fminf(gy1, ay1);
  float w = fmaxf(rbx - ltx, 0.0f), h = fmaxf(rby - lty, 0.0f);
  inter = w * h;
  uni = (garea + aarea) - inter;
}

__device__ __forceinline__ void top4_insert(u64 (&top)[4], u64 key) {
  if (key > top[3]) {
    if (key > top[0])      { top[3]=top[2]; top[2]=top[1]; top[1]=top[0]; top[0]=key; }
    else if (key > top[1]) { top[3]=top[2]; top[2]=top[1]; top[1]=key; }
    else if (key > top[2]) { top[3]=top[2]; top[2]=key; }
    else                   { top[3]=key; }
  }
}

__device__ __forceinline__ void wave_merge_top4(u64 (&top)[4]) {
  for (int off = 32; off >= 1; off >>= 1) {
    u64 o[4];
    #pragma unroll
    for (int k = 0; k < 4; k++) o[k] = __shfl_down(top[k], (unsigned)off);
    u64 m[4]; int i = 0, j = 0;
    #pragma unroll
    for (int k = 0; k < 4; k++) m[k] = (top[i] >= o[j]) ? top[i++] : o[j++];
    #pragma unroll
    for (int k = 0; k < 4; k++) top[k] = m[k];
  }
}

__device__ __forceinline__ void wave_merge_top4_u32(u32 (&top)[4]) {
  for (int off = 32; off >= 1; off >>= 1) {
    u32 o[4];
    #pragma unroll
    for (int k = 0; k < 4; k++) o[k] = __shfl_down(top[k], (unsigned)off);
    u32 m[4]; int i = 0, j = 0;
    #pragma unroll
    for (int k = 0; k < 4; k++) m[k] = (top[i] >= o[j]) ? top[i++] : o[j++];
    #pragma unroll
    for (int k = 0; k < 4; k++) top[k] = m[k];
  }
}

// conservative screen threshold: t~ = bitcast(max(tau,8)-8)  (tau = f32 bits)
__device__ __forceinline__ float screen_thresh(u32 tau) {
  u32 tb = (tau > 8u) ? (tau - 8u) : 0u;
  return __uint_as_float(tb);
}

// ---------------- Kernel 0: sampled threshold pass ----------------
// grid (SUB_NS, B); block 512 = 8 waves; wave w handles gt-groups {2w, 2w+1}.
// Per (slice,gt): Q4 = 4th-largest of the 64 lane maxima of approx q. Raw Q4
// written to thr_part[b][s][gt]; k_main reduces with max over s.
// Also zeroes the small per-image state (cnt/npos/fcnt) in the s==0 blocks.
__launch_bounds__(512, 4)
__global__ void k_thresh(const float4* __restrict__ anchors, const float4* __restrict__ gt,
                         u32* __restrict__ thr_part,
                         u32* __restrict__ npos, u32* __restrict__ fcnt,
                         u32* __restrict__ cnt) {
  const int s = blockIdx.x;        // 0..SUB_NS-1, all full slices
  const int b = blockIdx.y;
  const int t = threadIdx.x;
  const int wave = t >> 6, lane = t & 63;

  __shared__ float4 sxy[AS];
  __shared__ float  sg[5][64];

  if (s == 0) {
    if (t < 64) cnt[b * G_N + t] = 0;
    if (t == 0) { fcnt[b] = 0; npos[b] = 0; }
  }

  const int base = s * AS;
  const float4* ab = anchors + (size_t)b * A_N + base;

  for (int j = t; j < AS; j += 512) {
    float x0, y0, x1, y1, ar;
    conv_box(ab[j], x0, y0, x1, y1, ar);
    sxy[j] = make_float4(x0, y0, x1, y1);
  }
  if (t < 64) {
    float x0, y0, x1, y1, ar;
    conv_box(gt[(size_t)b * G_N + t], x0, y0, x1, y1, ar);
    sg[0][t] = x0; sg[1][t] = y0; sg[2][t] = x1; sg[3][t] = y1; sg[4][t] = ar;
  }
  __syncthreads();

  for (int gg = 0; gg < 2; gg++) {
    const int gi = (wave * 2 + gg) * 4;
    const float g0x0 = sg[0][gi],   g0y0 = sg[1][gi],   g0x1 = sg[2][gi],   g0y1 = sg[3][gi],   g0a = sg[4][gi];
    const float g1x0 = sg[0][gi+1], g1y0 = sg[1][gi+1], g1x1 = sg[2][gi+1], g1y1 = sg[3][gi+1], g1a = sg[4][gi+1];
    const float g2x0 = sg[0][gi+2], g2y0 = sg[1][gi+2], g2x1 = sg[2][gi+2], g2y1 = sg[3][gi+2], g2a = sg[4][gi+2];
    const float g3x0 = sg[0][gi+3], g3y0 = sg[1][gi+3], g3x1 = sg[2][gi+3], g3y1 = sg[3][gi+3], g3a = sg[4][gi+3];

    u32 q0 = 0, q1 = 0, q2 = 0, q3 = 0;
    for (int j = lane; j < AS; j += 64) {
      float4 x = sxy[j];
      float aarea = (x.z - x.x) * (x.w - x.y);
      float i0, u0, i1, u1, i2, u2, i3, u3;
      iou_parts(x.x, x.y, x.z, x.w, aarea, g0x0, g0y0, g0x1, g0y1, g0a, i0, u0);
      iou_parts(x.x, x.y, x.z, x.w, aarea, g1x0, g1y0, g1x1, g1y1, g1a, i1, u1);
      iou_parts(x.x, x.y, x.z, x.w, aarea, g2x0, g2y0, g2x1, g2y1, g2a, i2, u2);
      iou_parts(x.x, x.y, x.z, x.w, aarea, g3x0, g3y0, g3x1, g3y1, g3a, i3, u3);
      q0 = max(q0, __float_as_uint(i0 * __builtin_amdgcn_rcpf(u0)));
      q1 = max(q1, __float_as_uint(i1 * __builtin_amdgcn_rcpf(u1)));
      q2 = max(q2, __float_as_uint(i2 * __builtin_amdgcn_rcpf(u2)));
      q3 = max(q3, __float_as_uint(i3 * __builtin_amdgcn_rcpf(u3)));
    }
    u32 Q0[4] = {q0,0,0,0}, Q1[4] = {q1,0,0,0}, Q2[4] = {q2,0,0,0}, Q3[4] = {q3,0,0,0};
    wave_merge_top4_u32(Q0);
    wave_merge_top4_u32(Q1);
    wave_merge_top4_u32(Q2);
    wave_merge_top4_u32(Q3);
    if (lane == 0) {
      u32* dst = thr_part + ((size_t)b * SUB_NS + s) * G_N + gi;
      dst[0] = Q0[3]; dst[1] = Q1[3]; dst[2] = Q2[3]; dst[3] = Q3[3];
    }
  }
}

// ---------------- Kernel 1: screened exact pass (single pass over all pairs) ----------------
// grid (NS, B); block 512 = 8 waves; wave w handles gt-groups {2w, 2w+1}
// (so each wave's >=0.7 mask stays within one 32-gt half).
// launch_bounds (512,4): VGPR cap 128 — no spill (R8's (512,8) spilled).
__launch_bounds__(512, 4)
__global__ void k_main(const float4* __restrict__ anchors, const float4* __restrict__ gt,
                       const u32* __restrict__ thr_part,
                       u64* __restrict__ partial,
                       u64* __restrict__ posA, u64* __restrict__ posB) {
  const int s = blockIdx.x;
  const int b = blockIdx.y;
  const int t = threadIdx.x;
  const int wave = t >> 6, lane = t & 63;

  __shared__ float4 sxy[AS];        // converted xyxy; reused as wm after gp loop
  __shared__ float  sg[5][64];
  __shared__ float  sthr[64];       // per-gt screen thresholds (slack applied)
  u32* wm = (u32*)sxy;

  const int base = s * AS;
  const int acnt = min(AS, A_N - base);
  const float4* ab = anchors + (size_t)b * A_N + base;

  for (int j = t; j < acnt; j += 512) {
    float x0, y0, x1, y1, ar;
    conv_box(ab[j], x0, y0, x1, y1, ar);
    sxy[j] = make_float4(x0, y0, x1, y1);
  }
  if (t < 64) {
    float x0, y0, x1, y1, ar;
    conv_box(gt[(size_t)b * G_N + t], x0, y0, x1, y1, ar);
    sg[0][t] = x0; sg[1][t] = y0; sg[2][t] = x1; sg[3][t] = y1; sg[4][t] = ar;
    // global sampled threshold for gt t: max over the SUB_NS slice Q4s,
    // then the standard 16-ulp rcp slack + (0.7f - 8ulp) cap + 8-ulp margin.
    u32 mx = 0;
    for (int ss = 0; ss < SUB_NS; ss++)
      mx = max(mx, thr_part[((size_t)b * SUB_NS + ss) * G_N + t]);
    const u32 L7 = 0x3F333333u - 8u;   // 0.7f bits - 8 ulp
    sthr[t] = screen_thresh(min(mx > 16u ? mx - 16u : 0u, L7));
  }
  __syncthreads();

  u32 m = 0;   // bit k: anchor base+64k+lane has iou>=0.7 vs any of this wave's gts
  for (int gg = 0; gg < 2; gg++) {
    const int gp = wave * 2 + gg;      // 0..15
    const int gi = gp * 4;             // global gt index of group start
    const float g0x0 = sg[0][gi],   g0y0 = sg[1][gi],   g0x1 = sg[2][gi],   g0y1 = sg[3][gi],   g0a = sg[4][gi];
    const float g1x0 = sg[0][gi+1], g1y0 = sg[1][gi+1], g1x1 = sg[2][gi+1], g1y1 = sg[3][gi+1], g1a = sg[4][gi+1];
    const float g2x0 = sg[0][gi+2], g2y0 = sg[1][gi+2], g2x1 = sg[2][gi+2], g2y1 = sg[3][gi+2], g2a = sg[4][gi+2];
    const float g3x0 = sg[0][gi+3], g3y0 = sg[1][gi+3], g3x1 = sg[2][gi+3], g3y1 = sg[3][gi+3], g3a = sg[4][gi+3];
    const float t0 = sthr[gi], t1 = sthr[gi+1], t2 = sthr[gi+2], t3 = sthr[gi+3];

    // ---- single screened exact pass: top-4 + >=0.7 bits ----
    u64 T0[4] = {0,0,0,0}, T1[4] = {0,0,0,0}, T2[4] = {0,0,0,0}, T3[4] = {0,0,0,0};
    u32 h0 = 0, h1 = 0, h2 = 0, h3 = 0;
    u32 bit = 1u;
    for (int j = lane; j < acnt; j += 64, bit <<= 1) {
      float4 x = sxy[j];
      float aarea = (x.z - x.x) * (x.w - x.y);
      float i0, u0, i1, u1, i2, u2, i3, u3;
      iou_parts(x.x, x.y, x.z, x.w, aarea, g0x0, g0y0, g0x1, g0y1, g0a, i0, u0);
      iou_parts(x.x, x.y, x.z, x.w, aarea, g1x0, g1y0, g1x1, g1y1, g1a, i1, u1);
      iou_parts(x.x, x.y, x.z, x.w, aarea, g2x0, g2y0, g2x1, g2y1, g2a, i2, u2);
      iou_parts(x.x, x.y, x.z, x.w, aarea, g3x0, g3y0, g3x1, g3y1, g3a, i3, u3);
      u32 ni = ~(u32)(base + j);
      bool s0 = (i0 >= t0 * u0), s1 = (i1 >= t1 * u1);
      bool s2 = (i2 >= t2 * u2), s3 = (i3 >= t3 * u3);
      if (__ballot(s0)) {
        float v = 0.0f;
        if (s0) { v = i0 / u0; if (v >= 0.7f) m |= bit; }
        u32 vb = __float_as_uint(v);
        bool ins = s0 && (vb >= h0);
        if (__ballot(ins)) {
          if (ins) top4_insert(T0, ((u64)vb << 32) | (u64)ni);
          h0 = (u32)(T0[3] >> 32);
        }
      }
      if (__ballot(s1)) {
        float v = 0.0f;
        if (s1) { v = i1 / u1; if (v >= 0.7f) m |= bit; }
        u32 vb = __float_as_uint(v);
        bool ins = s1 && (vb >= h1);
        if (__ballot(ins)) {
          if (ins) top4_insert(T1, ((u64)vb << 32) | (u64)ni);
          h1 = (u32)(T1[3] >> 32);
        }
      }
      if (__ballot(s2)) {
        float v = 0.0f;
        if (s2) { v = i2 / u2; if (v >= 0.7f) m |= bit; }
        u32 vb = __float_as_uint(v);
        bool ins = s2 && (vb >= h2);
        if (__ballot(ins)) {
          if (ins) top4_insert(T2, ((u64)vb << 32) | (u64)ni);
          h2 = (u32)(T2[3] >> 32);
        }
      }
      if (__ballot(s3)) {
        float v = 0.0f;
        if (s3) { v = i3 / u3; if (v >= 0.7f) m |= bit; }
        u32 vb = __float_as_uint(v);
        bool ins = s3 && (vb >= h3);
        if (__ballot(ins)) {
          if (ins) top4_insert(T3, ((u64)vb << 32) | (u64)ni);
          h3 = (u32)(T3[3] >> 32);
        }
      }
    }
    wave_merge_top4(T0);
    wave_merge_top4(T1);
    wave_merge_top4(T2);
    wave_merge_top4(T3);
    if (lane == 0) {
      u64* dst = partial + (((size_t)b * NS + s) * G_N + gi) * 4;
      #pragma unroll
      for (int k = 0; k < 4; k++) {
        dst[k] = T0[k]; dst[4 + k] = T1[k]; dst[8 + k] = T2[k]; dst[12 + k] = T3[k];
      }
    }
  }

  __syncthreads();      // all waves done reading sxy (wm aliases it)
  wm[t] = m;
  __syncthreads();
  // waves 0-3 (threads 0..255) handled gts 0..31 -> posA; waves 4-7 -> posB.
  if (wave == 0 || wave == 4) {
    const u32* wmh = wm + (wave & 4) * 64;
    u32 mc = wmh[lane] | wmh[64 + lane] | wmh[128 + lane] | wmh[192 + lane];
    u64* posH = (wave ? posB : posA) + (size_t)b * NWORD + s * WPS;
    for (int k = 0; k < WPS; k++) {
      u64 bal = __ballot((mc >> k) & 1u);
      if (lane == 0) posH[k] = bal;    // plain store — every word covered exactly once
    }
  }
}

// ---------------- Kernel 2: merge partials -> top4; lq anchors -> posA ----------------
__launch_bounds__(64)
__global__ void k_top4_merge(const u64* __restrict__ partial, u64* __restrict__ top4,
                             u64* __restrict__ posA) {
  const int b = blockIdx.y, g = blockIdx.x, lane = threadIdx.x;
  const u64* pb = partial + ((size_t)b * NS * G_N + g) * 4;
  u64 keys[7];                       // NS*4 = 392 -> <= 7 per lane
  int nk = 0;
  for (int i = lane; i < NS * 4; i += 64)
    keys[nk++] = pb[(size_t)(i >> 2) * (G_N * 4) + (i & 3)];
  u64 top[4] = {0ull, 0ull, 0ull, 0ull};
  for (int q = 0; q < nk; q++) top4_insert(top, keys[q]);
  wave_merge_top4(top);
  if (lane == 0) {
    u64* dst = top4 + ((size_t)b * G_N + g) * 4;
    #pragma unroll
    for (int k = 0; k < 4; k++) dst[k] = top[k];
  }
  // low-quality matches: every partial entry whose value bits == hq bits.
  u32 hqb = (u32)(__shfl(top[0], 0) >> 32);
  for (int q = 0; q < nk; q++) {
    u64 key = keys[q];
    u32 aidx = ~(u32)key;
    if ((u32)(key >> 32) == hqb && aidx < A_N)
      atomicOr(&posA[(size_t)b * NWORD + (aidx >> 6)], 1ull << (aidx & 63));
  }
}

// ---------------- Kernel 3: zero hist (aliases dead partial; must run post-merge) ----------------
__launch_bounds__(256)
__global__ void k_zero(u32* __restrict__ hist) {
  int i = blockIdx.x * 256 + threadIdx.x;
  if (i < B_IMG * 4096) hist[i] = 0;
}

// ---------------- Kernel 4: word-parallel npos + global hist (cold: atomics OK) ----------------
// grid (13, B): thread handles word blockIdx.x*256 + t.
__launch_bounds__(256)
__global__ void k_hist(const u64* __restrict__ posA, const u64* __restrict__ posB,
                       u32* __restrict__ npos, u32* __restrict__ hist) {
  const int b = blockIdx.y;
  const int i = blockIdx.x * 256 + threadIdx.x;
  u32 k0, k1; image_key(b, k0, k1);
  u32 c = 0;
  if (i < NWORD) {
    u64 w = posA[(size_t)b * NWORD + i] | posB[(size_t)b * NWORD + i];
    c = (u32)__popcll(w);
    while (w) {
      int bit = __ffsll((long long)w) - 1; w &= w - 1;
      u32 a = (u32)(i * 64 + bit);
      atomicAdd(&hist[b * 4096 + (rbits_for(k0, k1, a) >> 20)], 1u);
    }
  }
  #pragma unroll
  for (int off = 32; off >= 1; off >>= 1) c += __shfl_xor(c, off);
  if ((threadIdx.x & 63) == 0 && c) atomicAdd(&npos[b], c);
}

// ---------------- Kernel 5: local bin selection + collect fine candidates ----------------
// grid (NS, B).
__launch_bounds__(256)
__global__ void k_collect(const u64* __restrict__ posA, const u64* __restrict__ posB,
                          const u32* __restrict__ npos, const u32* __restrict__ hist,
                          int2* __restrict__ binsel,
                          u32* __restrict__ fine, u32* __restrict__ fcnt) {
  const int b = blockIdx.y;
  const int t = threadIdx.x;
  __shared__ u32 red[256];
  __shared__ int sbin;

  const u32* hb = hist + b * 4096;
  u32 local = 0;
  for (int j = 0; j < 16; j++) local += hb[t * 16 + j];
  red[t] = local;
  __syncthreads();
  if (t == 0) {
    if (npos[b] <= MAX_POS) {
      sbin = -1;
      binsel[b] = make_int2(-1, 0);          // duplicate identical writes across blocks
    } else {
      u32 cum = 0; int chunk = 0;
      for (int i = 0; i < 256; i++) {
        if (cum + red[i] >= MAX_POS) { chunk = i; break; }
        cum += red[i];
      }
      int tb = chunk * 16; u32 before = cum;
      for (int j = 0; j < 16; j++) {
        u32 h = hb[chunk * 16 + j];
        if (before + h >= MAX_POS) { tb = chunk * 16 + j; break; }
        before += h;
      }
      sbin = tb;
      binsel[b] = make_int2(tb, (int)before);
    }
  }
  __syncthreads();
  const int stb = sbin;
  if (stb < 0) return;

  u32 k0, k1; image_key(b, k0, k1);
  const int a0 = blockIdx.x * AS;
  const u64* pa = posA + (size_t)b * NWORD;
  const u64* pb = posB + (size_t)b * NWORD;
  for (int j = t; j < AS; j += 256) {
    int a = a0 + j;
    if (a >= A_N) break;
    if (!(((pa[a >> 6] | pb[a >> 6]) >> (a & 63)) & 1ull)) continue;
    u32 rb = rbits_for(k0, k1, (u32)a);
    if ((int)(rb >> 20) != stb) continue;
    u32 idx = atomicAdd(&fcnt[b], 1u);
    if (idx < FINE_CAP) fine[b * FINE_CAP + idx] = (((rb >> 9) & 0x7FFu) << 18) | (u32)a;
  }
}

// ---------------- Kernel 6: local Tstar + per-gt counts of selected ----------------
// grid (NS, B).
__launch_bounds__(256)
__global__ void k_count(const float4* __restrict__ anchors, const float4* __restrict__ gt,
                        const u64* __restrict__ posA, const u64* __restrict__ posB,
                        const int2* __restrict__ binsel, const u32* __restrict__ fine,
                        const u32* __restrict__ fcnt, u32* __restrict__ cnt) {
  const int b = blockIdx.y;
  const int t = threadIdx.x;
  __shared__ float sg[5][64];
  __shared__ u64 sT;

  if (t < 64) {
    float x0, y0, x1, y1, ar;
    conv_box(gt[(size_t)b * G_N + t], x0, y0, x1, y1, ar);
    sg[0][t] = x0; sg[1][t] = y0; sg[2][t] = x1; sg[3][t] = y1; sg[4][t] = ar;
    // wave 0: compute Tstar locally (binary search over the small fine list)
    int2 bs = binsel[b];
    u64 T = ~0ull;
    if (bs.x >= 0) {
      const int m = min((int)fcnt[b], FINE_CAP);
      const u32 need = (u32)(MAX_POS - bs.y);   // >= 1
      const u32* fb = fine + b * FINE_CAP;
      u32 lo = 0, hi = (1u << 29) - 1;
      while (lo < hi) {
        u32 mid = lo + ((hi - lo) >> 1);
        u32 c = 0;
        for (int j = t; j < m; j += 64) c += (fb[j] <= mid) ? 1u : 0u;
        #pragma unroll
        for (int off = 32; off >= 1; off >>= 1) c += __shfl_xor(c, off);
        if (c >= need) hi = mid; else lo = mid + 1;   // uniform across wave
      }
      T = ((u64)(u32)bs.x << 29) | (u64)lo;   // 41-bit threshold
    }
    if (t == 0) sT = T;
  }
  __syncthreads();

  u32 k0, k1; image_key(b, k0, k1);
  const u64 T = sT;
  const int a0 = blockIdx.x * AS;
  const u64* pa = posA + (size_t)b * NWORD;
  const u64* pb = posB + (size_t)b * NWORD;
  const float4* ab = anchors + (size_t)b * A_N;
  for (int j = t; j < AS; j += 256) {
    int a = a0 + j;
    if (a >= A_N) break;
    if (!(((pa[a >> 6] | pb[a >> 6]) >> (a & 63)) & 1ull)) continue;
    if (T != ~0ull) {
      u32 rb = rbits_for(k0, k1, (u32)a);
      if (((((u64)(rb >> 9)) << 18) | (u64)(u32)a) > T) continue;
    }
    float ax0, ay0, ax1, ay1, aar;
    conv_box(ab[a], ax0, ay0, ax1, ay1, aar);
    float bv = -1.0f; int g0 = 0;
    for (int g = 0; g < 64; g++) {
      float v = iou_pair(ax0, ay0, ax1, ay1, aar,
                         sg[0][g], sg[1][g], sg[2][g], sg[3][g], sg[4][g]);
      if (v > bv) { bv = v; g0 = g; }   // strict > = first max (jnp.argmax)
    }
    atomicAdd(&cnt[b * G_N + g0], 1u);
  }
}

// ---------------- Kernel 7: output ----------------
__launch_bounds__(64)
__global__ void k_out(const u64* __restrict__ top4, const u32* __restrict__ cnt,
                      float* __restrict__ out, int sec) {
  const int b = blockIdx.x;
  const int g = threadIdx.x;   // 64 threads
  const u32 c = min(cnt[b * G_N + g], (u32)K_TOP);
  const u64* t4 = top4 + ((size_t)b * G_N + g) * 4;
  #pragma unroll
  for (int k = 0; k < 4; k++) {
    u64 key = t4[k];
    u32 fb = (u32)(key >> 32);
    u32 aidx = ~(u32)key;
    bool valid = (u32)k < c;
    int o = b * (G_N * K_TOP) + g * K_TOP + k;
    out[0 * sec + o] = valid ? (float)aidx : -1.0f;          // pr_inds
    out[1 * sec + o] = valid ? (float)g : -1.0f;             // gt_inds
    out[2 * sec + o] = valid ? 1.0f : 0.0f;                  // valid mask
    out[3 * sec + o] = valid ? __uint_as_float(fb) : 0.0f;   // topk ious
  }
}

extern "C" void kernel_launch(void* const* d_in, const int* in_sizes, int n_in,
                              void* d_out, int out_size, void* d_ws, size_t ws_size,
                              hipStream_t stream) {
  const float4* anchors = (const float4*)d_in[0];  // [B, A, 4] cxcywh
  const float4* gt      = (const float4*)d_in[1];  // [B, G, 4] cxcywh
  float* out = (float*)d_out;                      // 4 x [B, G*K] concatenated

  // Layout — IDENTICAL EXTENT to the R5/R7/R9-proven 2,025,536 B:
  //   top4    @ 0          (16,384)
  //     alias: thr_part @ 0 (8*8*64*4 = 16,384) [written k_thresh, read k_main,
  //            dead once k_top4_merge overwrites top4]
  //   partial @ 16,384     (8*98*64*32 = 1,605,632) — dead after k_top4_merge;
  //     aliases (written only in dispatches >= 4):
  //       fine   @ 16,384    (131,072)  [k_collect]
  //       hist   @ 147,456   (131,072)  [zeroed by k_zero post-merge]
  //       binsel @ 278,528   (64)       [k_collect]
  //   posA    @ 1,622,016  (200,704)  [fully ballot-stored — no init]
  //   posB    @ 1,822,720  (200,704)  [fully ballot-stored — no init]
  //   small   @ 2,023,424  (2,112): npos(32) fcnt(32) cnt(2,048)
  //            [zeroed by k_thresh s==0 blocks]
  char* ws = (char*)d_ws;
  u64*  top4    = (u64*)(ws);
  u32*  thr_prt = (u32*)(ws);
  u64*  partial = (u64*)(ws + 16384);
  u32*  fine    = (u32*)(ws + 16384);
  u32*  hist    = (u32*)(ws + 147456);
  int2* binsel  = (int2*)(ws + 278528);
  u64*  posA    = (u64*)(ws + 1622016);
  u64*  posB    = (u64*)(ws + 1822720);
  u32*  npos    = (u32*)(ws + 2023424);
  u32*  fcnt    = (u32*)(ws + 2023456);
  u32*  cnt     = (u32*)(ws + 2023488);

  int sec = out_size / 4;  // 2048 = B*G*K

  k_thresh    <<<dim3(SUB_NS, B_IMG), 512, 0, stream>>>(anchors, gt, thr_prt, npos, fcnt, cnt);
  k_main      <<<dim3(NS, B_IMG), 512, 0, stream>>>(anchors, gt, thr_prt, partial, posA, posB);
  k_top4_merge<<<dim3(G_N, B_IMG), 64, 0, stream>>>(partial, top4, posA);
  k_zero      <<<dim3(128), 256, 0, stream>>>(hist);
  k_hist      <<<dim3(13, B_IMG), 256, 0, stream>>>(posA, posB, npos, hist);
  k_collect   <<<dim3(NS, B_IMG), 256, 0, stream>>>(posA, posB, npos, hist, binsel, fine, fcnt);
  k_count     <<<dim3(NS, B_IMG), 256, 0, stream>>>(anchors, gt, posA, posB, binsel, fine, fcnt, cnt);
  k_out       <<<dim3(B_IMG), 64, 0, stream>>>(top4, cnt, out, sec);
}